// Round 3
// baseline (374.233 us; speedup 1.0000x reference)
//
#include <hip/hip_runtime.h>
#include <stdint.h>

// HydraAttention on MI355X (gfx950), R3.
// cvt3 -> bf16 | detect mask | GEMM1 qkv (32x32x16 mfma, BK=64) |
// rownorm+kv (2048 blocks) | GEMM2 fused A=q_hat*kv, pipelined frag loads,
// kv staged in LDS.

typedef short  short8   __attribute__((ext_vector_type(8)));
typedef float  floatx16 __attribute__((ext_vector_type(16)));

#define BM 128
#define BN 128
#define BK 64

__device__ __forceinline__ void async16(const void* g, void* l) {
  __builtin_amdgcn_global_load_lds((const __attribute__((address_space(1))) void*)g,
                                   (__attribute__((address_space(3))) void*)l, 16, 0, 0);
}

__device__ __forceinline__ uint16_t f2bf(float f) {  // RNE fp32->bf16
  union { float f; uint32_t u; } x; x.f = f;
  uint32_t u = x.u;
  return (uint16_t)((u + 0x7fffu + ((u >> 16) & 1u)) >> 16);
}
__device__ __forceinline__ float bf2f(uint16_t h) {
  union { uint32_t u; float f; } x; x.u = ((uint32_t)h) << 16; return x.f;
}
__device__ __forceinline__ uint32_t pack2(float a, float b) {
  return (uint32_t)f2bf(a) | ((uint32_t)f2bf(b) << 16);
}
__device__ __forceinline__ void upk8(uint4 u, float* f) {
  f[0]=bf2f((uint16_t)u.x); f[1]=bf2f((uint16_t)(u.x>>16));
  f[2]=bf2f((uint16_t)u.y); f[3]=bf2f((uint16_t)(u.y>>16));
  f[4]=bf2f((uint16_t)u.z); f[5]=bf2f((uint16_t)(u.z>>16));
  f[6]=bf2f((uint16_t)u.w); f[7]=bf2f((uint16_t)(u.w>>16));
}

// ---------------- fused fp32->bf16 convert of 3 buffers ----------------
__global__ __launch_bounds__(256) void cvt3(
    const float* __restrict__ a, uint16_t* __restrict__ ao, int na,
    const float* __restrict__ b, uint16_t* __restrict__ bo, int nb,
    const float* __restrict__ c, uint16_t* __restrict__ co, int nc) {
  int i = blockIdx.x * 256 + threadIdx.x;
  const float* in; uint16_t* out; int j = i;
  if (j < na) { in = a; out = ao; }
  else {
    j -= na;
    if (j < nb) { in = b; out = bo; }
    else { j -= nb; if (j >= nc) return; in = c; out = co; }
  }
  const float4* p = (const float4*)in;
  float4 u = p[(size_t)j * 2], v = p[(size_t)j * 2 + 1];
  uint4 o;
  o.x = pack2(u.x, u.y); o.y = pack2(u.z, u.w);
  o.z = pack2(v.x, v.y); o.w = pack2(v.z, v.w);
  ((uint4*)out)[j] = o;
}

// ---------------- GEMM1: qkv[M,N] = bf16( A[M,K] @ B[N,K]^T + bias ) -------
// 128x128 tile, BK=64, 4 waves as 2x2 of 64x64, each wave 2x2 of 32x32x16 mfma.
// LDS chunk (16B) for (row,kc): index = row*8 + (kc ^ (row&7))  [XOR swizzle]
__global__ __launch_bounds__(256, 2) void gemm1(
    const uint16_t* __restrict__ A, const uint16_t* __restrict__ Bw,
    const float* __restrict__ bias, uint16_t* __restrict__ Cb,
    int N, int K)
{
  __shared__ __align__(16) uint16_t As[BM * BK];
  __shared__ __align__(16) uint16_t Bs[BN * BK];
  const int tid = threadIdx.x;
  const int wave = tid >> 6, lane = tid & 63;
  const int l31 = lane & 31, khalf = lane >> 5;
  const int wm = wave & 1, wn = wave >> 1;
  const int tileM = blockIdx.y * BM, tileN = blockIdx.x * BN;

  const int srow = wave * 8 + (lane >> 3);
  const int skc  = (lane & 7) ^ (lane >> 3);
  const uint16_t* gA = A  + (size_t)(tileM + srow) * K + skc * 8;
  const uint16_t* gB = Bw + (size_t)(tileN + srow) * K + skc * 8;
  char* lA = (char*)As + wave * 64 * 16;
  char* lB = (char*)Bs + wave * 64 * 16;

  floatx16 acc[2][2];
#pragma unroll
  for (int mi = 0; mi < 2; mi++)
#pragma unroll
    for (int ni = 0; ni < 2; ni++)
#pragma unroll
      for (int r = 0; r < 16; r++) acc[mi][ni][r] = 0.f;

  const int arow0 = wm * 64 + l31;
  const int brow0 = wn * 64 + l31;

  for (int k0 = 0; k0 < K; k0 += BK) {
#pragma unroll
    for (int s = 0; s < 4; s++) {
      async16(gA + k0 + s * 32 * K, lA + s * 4096);
      async16(gB + k0 + s * 32 * K, lB + s * 4096);
    }
    __syncthreads();
#pragma unroll
    for (int ks = 0; ks < 4; ks++) {
      const int kc = khalf + ks * 2;
      short8 af[2], bfr[2];
#pragma unroll
      for (int mi = 0; mi < 2; mi++) {
        int r = arow0 + mi * 32;
        af[mi] = *(const short8*)&As[(r * 8 + (kc ^ (r & 7))) * 8];
      }
#pragma unroll
      for (int ni = 0; ni < 2; ni++) {
        int r = brow0 + ni * 32;
        bfr[ni] = *(const short8*)&Bs[(r * 8 + (kc ^ (r & 7))) * 8];
      }
#pragma unroll
      for (int mi = 0; mi < 2; mi++)
#pragma unroll
        for (int ni = 0; ni < 2; ni++)
          acc[mi][ni] = __builtin_amdgcn_mfma_f32_32x32x16_bf16(af[mi], bfr[ni], acc[mi][ni], 0, 0, 0);
    }
    __syncthreads();
  }

  // C/D layout 32x32: col = lane&31, row = (reg&3) + 8*(reg>>2) + 4*(lane>>5)
#pragma unroll
  for (int mi = 0; mi < 2; mi++) {
    int rbase = tileM + wm * 64 + mi * 32 + 4 * khalf;
#pragma unroll
    for (int ni = 0; ni < 2; ni++) {
      int col = tileN + wn * 64 + ni * 32 + l31;
      float bv = bias[col];
#pragma unroll
      for (int reg = 0; reg < 16; reg++) {
        int row = rbase + (reg & 3) + 8 * (reg >> 2);
        Cb[(size_t)row * N + col] = f2bf(acc[mi][ni][reg] + bv);
      }
    }
  }
}

// ---------------- GEMM2: out = (q_hat*kv) @ Wout^T + bias, N=K=1024 --------
// A built on the fly from qkv + invq + kv(LDS); frag loads pipelined one
// iteration ahead so their latency is covered by the MFMA phase.
__global__ __launch_bounds__(256, 2) void gemm2(
    const uint16_t* __restrict__ qkv, const float* __restrict__ invq,
    const float* __restrict__ kv, const uint16_t* __restrict__ Bw,
    const float* __restrict__ bias, float* __restrict__ Cf)
{
  __shared__ __align__(16) uint16_t As[BM * BK];
  __shared__ __align__(16) uint16_t Bs[BN * BK];
  __shared__ __align__(16) float kvs[1024];
  const int tid = threadIdx.x;
  const int wave = tid >> 6, lane = tid & 63;
  const int l31 = lane & 31, khalf = lane >> 5;
  const int wm = wave & 1, wn = wave >> 1;
  const int tileM = blockIdx.y * BM, tileN = blockIdx.x * BN;

  const int srow = wave * 8 + (lane >> 3);
  const int skc  = (lane & 7) ^ (lane >> 3);
  const uint16_t* gB = Bw + (size_t)(tileN + srow) * 1024 + skc * 8;
  char* lB = (char*)Bs + wave * 64 * 16;

  // stage kv[b] (4 KB) into LDS
  {
    int i = tid * 4;
    *(float4*)&kvs[i] = *(const float4*)(kv + ((tileM >> 12) << 10) + i);
  }
  float sinv[4];
#pragma unroll
  for (int s = 0; s < 4; s++) sinv[s] = invq[tileM + s * 32 + srow];

  floatx16 acc[2][2];
#pragma unroll
  for (int mi = 0; mi < 2; mi++)
#pragma unroll
    for (int ni = 0; ni < 2; ni++)
#pragma unroll
      for (int r = 0; r < 16; r++) acc[mi][ni][r] = 0.f;

  const int arow0 = wm * 64 + l31;
  const int brow0 = wn * 64 + l31;

  const uint16_t* qbase = qkv + (size_t)(tileM + srow) * 3072 + skc * 8;
  uint4 nq[4];
#pragma unroll
  for (int s = 0; s < 4; s++)
    nq[s] = *(const uint4*)(qbase + (size_t)s * 32 * 3072);

  __syncthreads();  // kvs ready

#pragma unroll 2
  for (int k0 = 0; k0 < 1024; k0 += BK) {
    uint4 cq[4];
#pragma unroll
    for (int s = 0; s < 4; s++) cq[s] = nq[s];
    if (k0 + BK < 1024) {
#pragma unroll
      for (int s = 0; s < 4; s++)
        nq[s] = *(const uint4*)(qbase + (size_t)s * 32 * 3072 + k0 + BK);
    }
#pragma unroll
    for (int s = 0; s < 4; s++)
      async16(gB + k0 + s * 32 * 1024, lB + s * 4096);
#pragma unroll
    for (int s = 0; s < 4; s++) {
      int d = k0 + skc * 8;
      float4 k0v = *(const float4*)&kvs[d];
      float4 k1v = *(const float4*)&kvs[d + 4];
      float qf[8]; upk8(cq[s], qf);
      float sc = sinv[s];
      uint4 o;
      o.x = pack2(qf[0] * sc * k0v.x, qf[1] * sc * k0v.y);
      o.y = pack2(qf[2] * sc * k0v.z, qf[3] * sc * k0v.w);
      o.z = pack2(qf[4] * sc * k1v.x, qf[5] * sc * k1v.y);
      o.w = pack2(qf[6] * sc * k1v.z, qf[7] * sc * k1v.w);
      *(uint4*)((char*)As + (size_t)(s * 256 + wave * 64 + lane) * 16) = o;
    }
    __syncthreads();
#pragma unroll
    for (int ks = 0; ks < 4; ks++) {
      const int kc = khalf + ks * 2;
      short8 af[2], bfr[2];
#pragma unroll
      for (int mi = 0; mi < 2; mi++) {
        int r = arow0 + mi * 32;
        af[mi] = *(const short8*)&As[(r * 8 + (kc ^ (r & 7))) * 8];
      }
#pragma unroll
      for (int ni = 0; ni < 2; ni++) {
        int r = brow0 + ni * 32;
        bfr[ni] = *(const short8*)&Bs[(r * 8 + (kc ^ (r & 7))) * 8];
      }
#pragma unroll
      for (int mi = 0; mi < 2; mi++)
#pragma unroll
        for (int ni = 0; ni < 2; ni++)
          acc[mi][ni] = __builtin_amdgcn_mfma_f32_32x32x16_bf16(af[mi], bfr[ni], acc[mi][ni], 0, 0, 0);
    }
    __syncthreads();
  }

#pragma unroll
  for (int mi = 0; mi < 2; mi++) {
    int rbase = tileM + wm * 64 + mi * 32 + 4 * khalf;
#pragma unroll
    for (int ni = 0; ni < 2; ni++) {
      int col = tileN + wn * 64 + ni * 32 + l31;
      float bv = bias[col];
#pragma unroll
      for (int reg = 0; reg < 16; reg++) {
        int row = rbase + (reg & 3) + 8 * (reg >> 2);
        Cf[(size_t)row * 1024 + col] = acc[mi][ni][reg] + bv;
      }
    }
  }
}

// ---------------- mask layout detection ----------------
__global__ __launch_bounds__(256) void detect_mask(const unsigned char* __restrict__ m,
                                                   int* __restrict__ flag) {
  int i = blockIdx.x * blockDim.x + threadIdx.x;
  int v = ((i & 3) != 0) ? (int)m[i] : 0;
  unsigned long long b = __ballot(v != 0);
  if ((threadIdx.x & 63) == 0 && b) atomicOr(flag, 1);
}

// ---------------- per-row norms + kv reduction ----------------
// 2048 blocks: 8 rows/block, 2 rows/wave. Lane owns d in [lane*16, lane*16+16).
__global__ __launch_bounds__(256) void rownorm_kv(
    const uint16_t* __restrict__ qkv, const void* __restrict__ maskbuf,
    const int* __restrict__ flag, float* __restrict__ invq, float* __restrict__ kv)
{
  __shared__ float kvloc[1024];
  const int tid = threadIdx.x;
  for (int i = tid; i < 1024; i += 256) kvloc[i] = 0.f;
  __syncthreads();
  const int wave = tid >> 6, lane = tid & 63;
  const int b = blockIdx.x >> 9;
  const int isU8 = *flag;
  const unsigned char* m8 = (const unsigned char*)maskbuf;
  const int* m32 = (const int*)maskbuf;

  float kvacc[16];
#pragma unroll
  for (int i = 0; i < 16; i++) kvacc[i] = 0.f;

  const int r0 = blockIdx.x * 8 + wave * 2;
#pragma unroll
  for (int j = 0; j < 2; j++) {
    int r = r0 + j;
    const uint16_t* rp = qkv + (size_t)r * 3072;
    uint4 q0 = *(const uint4*)(rp + lane * 16);
    uint4 q1 = *(const uint4*)(rp + lane * 16 + 8);
    uint4 k0 = *(const uint4*)(rp + 1024 + lane * 16);
    uint4 k1 = *(const uint4*)(rp + 1024 + lane * 16 + 8);
    uint4 v0 = *(const uint4*)(rp + 2048 + lane * 16);
    uint4 v1 = *(const uint4*)(rp + 2048 + lane * 16 + 8);
    float qf[16], kf[16], vf[16];
    upk8(q0, qf); upk8(q1, qf + 8);
    upk8(k0, kf); upk8(k1, kf + 8);
    upk8(v0, vf); upk8(v1, vf + 8);
    float sq = 0.f, sk = 0.f;
#pragma unroll
    for (int i = 0; i < 16; i++) { sq = fmaf(qf[i], qf[i], sq); sk = fmaf(kf[i], kf[i], sk); }
    for (int off = 32; off; off >>= 1) { sq += __shfl_xor(sq, off); sk += __shfl_xor(sk, off); }
    float rq = rsqrtf(sq), rk = rsqrtf(sk);
    if (lane == 0) invq[r] = rq;
    int masked = isU8 ? (int)m8[r] : m32[r];
    if (!masked) {
#pragma unroll
      for (int i = 0; i < 16; i++) kvacc[i] = fmaf(kf[i] * rk, vf[i], kvacc[i]);
    }
  }
#pragma unroll
  for (int i = 0; i < 16; i++) atomicAdd(&kvloc[lane * 16 + i], kvacc[i]);
  __syncthreads();
  for (int i = tid; i < 1024; i += 256) atomicAdd(&kv[b * 1024 + i], kvloc[i]);
}

extern "C" void kernel_launch(void* const* d_in, const int* in_sizes, int n_in,
                              void* d_out, int out_size, void* d_ws, size_t ws_size,
                              hipStream_t stream) {
  const float* x     = (const float*)d_in[0];
  const void*  mask  = d_in[1];
  const float* W_qkv = (const float*)d_in[2];
  const float* b_qkv = (const float*)d_in[3];
  const float* W_out = (const float*)d_in[4];
  const float* b_out = (const float*)d_in[5];
  float* out = (float*)d_out;

  const int BT = 4 * 4096;  // 16384 rows
  const int D  = 1024;

  char* ws = (char*)d_ws;
  size_t off = 0;
  auto alloc = [&](size_t bytes) { size_t r = off; off += (bytes + 255) & ~(size_t)255; return r; };
  size_t o_xb   = alloc((size_t)BT * D * 2);        // x bf16
  size_t o_qkvb = alloc((size_t)BT * 3 * D * 2);    // qkv bf16
  size_t o_wq   = alloc((size_t)3 * D * D * 2);     // W_qkv bf16
  size_t o_wo   = alloc((size_t)D * D * 2);         // W_out bf16
  size_t o_kv   = alloc((size_t)4 * D * 4 + 256);   // kv (fp32) + flag
  size_t o_invq = alloc((size_t)BT * 4);            // 1/||q|| per row

  uint16_t* xb   = (uint16_t*)(ws + o_xb);
  uint16_t* qkvb = (uint16_t*)(ws + o_qkvb);
  uint16_t* wq   = (uint16_t*)(ws + o_wq);
  uint16_t* wo   = (uint16_t*)(ws + o_wo);
  float*    kv   = (float*)(ws + o_kv);
  int*      flag = (int*)(ws + o_kv + (size_t)4 * D * 4);
  float*    invq = (float*)(ws + o_invq);

  hipMemsetAsync(ws + o_kv, 0, (size_t)4 * D * 4 + 256, stream);
  {
    int na = BT * D / 8, nb = 3 * D * D / 8, nc = D * D / 8;
    int tot = na + nb + nc;
    cvt3<<<dim3((tot + 255) / 256), 256, 0, stream>>>(x, xb, na, W_qkv, wq, nb, W_out, wo, nc);
  }
  detect_mask<<<dim3(64), 256, 0, stream>>>((const unsigned char*)mask, flag);
  gemm1<<<dim3(3 * D / BN, BT / BM), 256, 0, stream>>>(xb, wq, b_qkv, qkvb, 3 * D, D);
  rownorm_kv<<<dim3(2048), 256, 0, stream>>>(qkvb, mask, flag, invq, kv);
  gemm2<<<dim3(D / BN, BT / BM), 256, 0, stream>>>(qkvb, invq, kv, wo, b_out, out);
}

// Round 4
// 333.256 us; speedup vs baseline: 1.1230x; 1.1230x over previous
//
#include <hip/hip_runtime.h>
#include <stdint.h>

// HydraAttention on MI355X (gfx950), R4.
// R2 base + XCD-aware grid swizzle on both GEMMs (per-XCD N-slab, uniform M
// sweep -> A served by L3, B resident in per-XCD L2) + kv staged in LDS in
// gemm2. rownorm back to 512 blocks (R3's 2048-block version regressed).

typedef short  short8   __attribute__((ext_vector_type(8)));
typedef float  floatx16 __attribute__((ext_vector_type(16)));

#define BM 128
#define BN 128
#define BK 64

__device__ __forceinline__ void async16(const void* g, void* l) {
  __builtin_amdgcn_global_load_lds((const __attribute__((address_space(1))) void*)g,
                                   (__attribute__((address_space(3))) void*)l, 16, 0, 0);
}

__device__ __forceinline__ uint16_t f2bf(float f) {  // RNE fp32->bf16
  union { float f; uint32_t u; } x; x.f = f;
  uint32_t u = x.u;
  return (uint16_t)((u + 0x7fffu + ((u >> 16) & 1u)) >> 16);
}
__device__ __forceinline__ float bf2f(uint16_t h) {
  union { uint32_t u; float f; } x; x.u = ((uint32_t)h) << 16; return x.f;
}
__device__ __forceinline__ uint32_t pack2(float a, float b) {
  return (uint32_t)f2bf(a) | ((uint32_t)f2bf(b) << 16);
}
__device__ __forceinline__ void upk8(uint4 u, float* f) {
  f[0]=bf2f((uint16_t)u.x); f[1]=bf2f((uint16_t)(u.x>>16));
  f[2]=bf2f((uint16_t)u.y); f[3]=bf2f((uint16_t)(u.y>>16));
  f[4]=bf2f((uint16_t)u.z); f[5]=bf2f((uint16_t)(u.z>>16));
  f[6]=bf2f((uint16_t)u.w); f[7]=bf2f((uint16_t)(u.w>>16));
}

// ---------------- fused fp32->bf16 convert of 3 buffers ----------------
__global__ __launch_bounds__(256) void cvt3(
    const float* __restrict__ a, uint16_t* __restrict__ ao, int na,
    const float* __restrict__ b, uint16_t* __restrict__ bo, int nb,
    const float* __restrict__ c, uint16_t* __restrict__ co, int nc) {
  int i = blockIdx.x * 256 + threadIdx.x;
  const float* in; uint16_t* out; int j = i;
  if (j < na) { in = a; out = ao; }
  else {
    j -= na;
    if (j < nb) { in = b; out = bo; }
    else { j -= nb; if (j >= nc) return; in = c; out = co; }
  }
  const float4* p = (const float4*)in;
  float4 u = p[(size_t)j * 2], v = p[(size_t)j * 2 + 1];
  uint4 o;
  o.x = pack2(u.x, u.y); o.y = pack2(u.z, u.w);
  o.z = pack2(v.x, v.y); o.w = pack2(v.z, v.w);
  ((uint4*)out)[j] = o;
}

// ---------------- GEMM1: qkv[M,N] = bf16( A[M,K] @ B[N,K]^T + bias ) -------
// 1D grid, 3072 blocks. Swizzle: xcd = id&7 owns N-slab of 3 tiles (B slab
// 768 KB resident in that XCD's L2); m = (id>>3)/3 advances uniformly so all
// 24 blocks sharing an A-tile dispatch within a 24-id window (A via L3).
__global__ __launch_bounds__(256, 2) void gemm1(
    const uint16_t* __restrict__ A, const uint16_t* __restrict__ Bw,
    const float* __restrict__ bias, uint16_t* __restrict__ Cb,
    int N, int K)
{
  __shared__ __align__(16) uint16_t As[BM * BK];
  __shared__ __align__(16) uint16_t Bs[BN * BK];
  const int tid = threadIdx.x;
  const int wave = tid >> 6, lane = tid & 63;
  const int l31 = lane & 31, khalf = lane >> 5;
  const int wm = wave & 1, wn = wave >> 1;
  const int id = blockIdx.x;
  const int xcd = id & 7, w = id >> 3;
  const int tileM = (w / 3) * BM;
  const int tileN = (xcd * 3 + (w % 3)) * BN;

  const int srow = wave * 8 + (lane >> 3);
  const int skc  = (lane & 7) ^ (lane >> 3);
  const uint16_t* gA = A  + (size_t)(tileM + srow) * K + skc * 8;
  const uint16_t* gB = Bw + (size_t)(tileN + srow) * K + skc * 8;
  char* lA = (char*)As + wave * 64 * 16;
  char* lB = (char*)Bs + wave * 64 * 16;

  floatx16 acc[2][2];
#pragma unroll
  for (int mi = 0; mi < 2; mi++)
#pragma unroll
    for (int ni = 0; ni < 2; ni++)
#pragma unroll
      for (int r = 0; r < 16; r++) acc[mi][ni][r] = 0.f;

  const int arow0 = wm * 64 + l31;
  const int brow0 = wn * 64 + l31;

  for (int k0 = 0; k0 < K; k0 += BK) {
#pragma unroll
    for (int s = 0; s < 4; s++) {
      async16(gA + k0 + s * 32 * K, lA + s * 4096);
      async16(gB + k0 + s * 32 * K, lB + s * 4096);
    }
    __syncthreads();
#pragma unroll
    for (int ks = 0; ks < 4; ks++) {
      const int kc = khalf + ks * 2;
      short8 af[2], bfr[2];
#pragma unroll
      for (int mi = 0; mi < 2; mi++) {
        int r = arow0 + mi * 32;
        af[mi] = *(const short8*)&As[(r * 8 + (kc ^ (r & 7))) * 8];
      }
#pragma unroll
      for (int ni = 0; ni < 2; ni++) {
        int r = brow0 + ni * 32;
        bfr[ni] = *(const short8*)&Bs[(r * 8 + (kc ^ (r & 7))) * 8];
      }
#pragma unroll
      for (int mi = 0; mi < 2; mi++)
#pragma unroll
        for (int ni = 0; ni < 2; ni++)
          acc[mi][ni] = __builtin_amdgcn_mfma_f32_32x32x16_bf16(af[mi], bfr[ni], acc[mi][ni], 0, 0, 0);
    }
    __syncthreads();
  }

  // C/D layout 32x32: col = lane&31, row = (reg&3) + 8*(reg>>2) + 4*(lane>>5)
#pragma unroll
  for (int mi = 0; mi < 2; mi++) {
    int rbase = tileM + wm * 64 + mi * 32 + 4 * khalf;
#pragma unroll
    for (int ni = 0; ni < 2; ni++) {
      int col = tileN + wn * 64 + ni * 32 + l31;
      float bv = bias[col];
#pragma unroll
      for (int reg = 0; reg < 16; reg++) {
        int row = rbase + (reg & 3) + 8 * (reg >> 2);
        Cb[(size_t)row * N + col] = f2bf(acc[mi][ni][reg] + bv);
      }
    }
  }
}

// ---------------- GEMM2: out = (q_hat*kv) @ Wout^T + bias, N=K=1024 --------
// 1D grid, 1024 blocks; xcd = id&7 owns exactly one N-tile. A built on the
// fly from qkv + invq + kv (kv staged once in LDS).
__global__ __launch_bounds__(256, 2) void gemm2(
    const uint16_t* __restrict__ qkv, const float* __restrict__ invq,
    const float* __restrict__ kv, const uint16_t* __restrict__ Bw,
    const float* __restrict__ bias, float* __restrict__ Cf)
{
  __shared__ __align__(16) uint16_t As[BM * BK];
  __shared__ __align__(16) uint16_t Bs[BN * BK];
  __shared__ __align__(16) float kvs[1024];
  const int tid = threadIdx.x;
  const int wave = tid >> 6, lane = tid & 63;
  const int l31 = lane & 31, khalf = lane >> 5;
  const int wm = wave & 1, wn = wave >> 1;
  const int id = blockIdx.x;
  const int tileM = (id >> 3) * BM;
  const int tileN = (id & 7) * BN;

  const int srow = wave * 8 + (lane >> 3);
  const int skc  = (lane & 7) ^ (lane >> 3);
  const uint16_t* gB = Bw + (size_t)(tileN + srow) * 1024 + skc * 8;
  char* lB = (char*)Bs + wave * 64 * 16;

  // stage kv[b] (4 KB) into LDS
  {
    int i = tid * 4;
    *(float4*)&kvs[i] = *(const float4*)(kv + ((tileM >> 12) << 10) + i);
  }
  float sinv[4];
#pragma unroll
  for (int s = 0; s < 4; s++) sinv[s] = invq[tileM + s * 32 + srow];

  floatx16 acc[2][2];
#pragma unroll
  for (int mi = 0; mi < 2; mi++)
#pragma unroll
    for (int ni = 0; ni < 2; ni++)
#pragma unroll
      for (int r = 0; r < 16; r++) acc[mi][ni][r] = 0.f;

  const int arow0 = wm * 64 + l31;
  const int brow0 = wn * 64 + l31;
  const uint16_t* qbase = qkv + (size_t)(tileM + srow) * 3072 + skc * 8;

  __syncthreads();  // kvs ready

  for (int k0 = 0; k0 < 1024; k0 += BK) {
#pragma unroll
    for (int s = 0; s < 4; s++)
      async16(gB + k0 + s * 32 * 1024, lB + s * 4096);
#pragma unroll
    for (int s = 0; s < 4; s++) {
      int d = k0 + skc * 8;
      uint4 qv = *(const uint4*)(qbase + (size_t)s * 32 * 3072 + k0);
      float4 k0v = *(const float4*)&kvs[d];
      float4 k1v = *(const float4*)&kvs[d + 4];
      float qf[8]; upk8(qv, qf);
      float sc = sinv[s];
      uint4 o;
      o.x = pack2(qf[0] * sc * k0v.x, qf[1] * sc * k0v.y);
      o.y = pack2(qf[2] * sc * k0v.z, qf[3] * sc * k0v.w);
      o.z = pack2(qf[4] * sc * k1v.x, qf[5] * sc * k1v.y);
      o.w = pack2(qf[6] * sc * k1v.z, qf[7] * sc * k1v.w);
      *(uint4*)((char*)As + (size_t)(s * 256 + wave * 64 + lane) * 16) = o;
    }
    __syncthreads();
#pragma unroll
    for (int ks = 0; ks < 4; ks++) {
      const int kc = khalf + ks * 2;
      short8 af[2], bfr[2];
#pragma unroll
      for (int mi = 0; mi < 2; mi++) {
        int r = arow0 + mi * 32;
        af[mi] = *(const short8*)&As[(r * 8 + (kc ^ (r & 7))) * 8];
      }
#pragma unroll
      for (int ni = 0; ni < 2; ni++) {
        int r = brow0 + ni * 32;
        bfr[ni] = *(const short8*)&Bs[(r * 8 + (kc ^ (r & 7))) * 8];
      }
#pragma unroll
      for (int mi = 0; mi < 2; mi++)
#pragma unroll
        for (int ni = 0; ni < 2; ni++)
          acc[mi][ni] = __builtin_amdgcn_mfma_f32_32x32x16_bf16(af[mi], bfr[ni], acc[mi][ni], 0, 0, 0);
    }
    __syncthreads();
  }

#pragma unroll
  for (int mi = 0; mi < 2; mi++) {
    int rbase = tileM + wm * 64 + mi * 32 + 4 * khalf;
#pragma unroll
    for (int ni = 0; ni < 2; ni++) {
      int col = tileN + wn * 64 + ni * 32 + l31;
      float bv = bias[col];
#pragma unroll
      for (int reg = 0; reg < 16; reg++) {
        int row = rbase + (reg & 3) + 8 * (reg >> 2);
        Cf[(size_t)row * 1024 + col] = acc[mi][ni][reg] + bv;
      }
    }
  }
}

// ---------------- mask layout detection ----------------
__global__ __launch_bounds__(256) void detect_mask(const unsigned char* __restrict__ m,
                                                   int* __restrict__ flag) {
  int i = blockIdx.x * blockDim.x + threadIdx.x;
  int v = ((i & 3) != 0) ? (int)m[i] : 0;
  unsigned long long b = __ballot(v != 0);
  if ((threadIdx.x & 63) == 0 && b) atomicOr(flag, 1);
}

// ---------------- per-row norms + kv reduction (R2 version, 512 blocks) ----
__global__ __launch_bounds__(256) void rownorm_kv(
    const uint16_t* __restrict__ qkv, const void* __restrict__ maskbuf,
    const int* __restrict__ flag, float* __restrict__ invq, float* __restrict__ kv)
{
  __shared__ float kvloc[1024];
  const int tid = threadIdx.x;
  for (int i = tid; i < 1024; i += 256) kvloc[i] = 0.f;
  __syncthreads();
  const int wave = tid >> 6, lane = tid & 63;
  const int b = blockIdx.x >> 7;
  const int chunk = blockIdx.x & 127;
  const int isU8 = *flag;
  const unsigned char* m8 = (const unsigned char*)maskbuf;
  const int* m32 = (const int*)maskbuf;

  float kvacc[16];
#pragma unroll
  for (int i = 0; i < 16; i++) kvacc[i] = 0.f;

  const int r0 = b * 4096 + chunk * 32 + wave * 8;
  for (int j = 0; j < 8; j++) {
    int r = r0 + j;
    const uint16_t* rp = qkv + (size_t)r * 3072;
    uint4 q0 = *(const uint4*)(rp + lane * 16);
    uint4 q1 = *(const uint4*)(rp + lane * 16 + 8);
    uint4 k0 = *(const uint4*)(rp + 1024 + lane * 16);
    uint4 k1 = *(const uint4*)(rp + 1024 + lane * 16 + 8);
    uint4 v0 = *(const uint4*)(rp + 2048 + lane * 16);
    uint4 v1 = *(const uint4*)(rp + 2048 + lane * 16 + 8);
    float qf[16], kf[16], vf[16];
    upk8(q0, qf); upk8(q1, qf + 8);
    upk8(k0, kf); upk8(k1, kf + 8);
    upk8(v0, vf); upk8(v1, vf + 8);
    float sq = 0.f, sk = 0.f;
#pragma unroll
    for (int i = 0; i < 16; i++) { sq = fmaf(qf[i], qf[i], sq); sk = fmaf(kf[i], kf[i], sk); }
    for (int off = 32; off; off >>= 1) { sq += __shfl_xor(sq, off); sk += __shfl_xor(sk, off); }
    float rq = rsqrtf(sq), rk = rsqrtf(sk);
    if (lane == 0) invq[r] = rq;
    int masked = isU8 ? (int)m8[r] : m32[r];
    if (!masked) {
#pragma unroll
      for (int i = 0; i < 16; i++) kvacc[i] = fmaf(kf[i] * rk, vf[i], kvacc[i]);
    }
  }
#pragma unroll
  for (int i = 0; i < 16; i++) atomicAdd(&kvloc[lane * 16 + i], kvacc[i]);
  __syncthreads();
  for (int i = tid; i < 1024; i += 256) atomicAdd(&kv[b * 1024 + i], kvloc[i]);
}

extern "C" void kernel_launch(void* const* d_in, const int* in_sizes, int n_in,
                              void* d_out, int out_size, void* d_ws, size_t ws_size,
                              hipStream_t stream) {
  const float* x     = (const float*)d_in[0];
  const void*  mask  = d_in[1];
  const float* W_qkv = (const float*)d_in[2];
  const float* b_qkv = (const float*)d_in[3];
  const float* W_out = (const float*)d_in[4];
  const float* b_out = (const float*)d_in[5];
  float* out = (float*)d_out;

  const int BT = 4 * 4096;  // 16384 rows
  const int D  = 1024;

  char* ws = (char*)d_ws;
  size_t off = 0;
  auto alloc = [&](size_t bytes) { size_t r = off; off += (bytes + 255) & ~(size_t)255; return r; };
  size_t o_xb   = alloc((size_t)BT * D * 2);        // x bf16
  size_t o_qkvb = alloc((size_t)BT * 3 * D * 2);    // qkv bf16
  size_t o_wq   = alloc((size_t)3 * D * D * 2);     // W_qkv bf16
  size_t o_wo   = alloc((size_t)D * D * 2);         // W_out bf16
  size_t o_kv   = alloc((size_t)4 * D * 4 + 256);   // kv (fp32) + flag
  size_t o_invq = alloc((size_t)BT * 4);            // 1/||q|| per row

  uint16_t* xb   = (uint16_t*)(ws + o_xb);
  uint16_t* qkvb = (uint16_t*)(ws + o_qkvb);
  uint16_t* wq   = (uint16_t*)(ws + o_wq);
  uint16_t* wo   = (uint16_t*)(ws + o_wo);
  float*    kv   = (float*)(ws + o_kv);
  int*      flag = (int*)(ws + o_kv + (size_t)4 * D * 4);
  float*    invq = (float*)(ws + o_invq);

  hipMemsetAsync(ws + o_kv, 0, (size_t)4 * D * 4 + 256, stream);
  {
    int na = BT * D / 8, nb = 3 * D * D / 8, nc = D * D / 8;
    int tot = na + nb + nc;
    cvt3<<<dim3((tot + 255) / 256), 256, 0, stream>>>(x, xb, na, W_qkv, wq, nb, W_out, wo, nc);
  }
  detect_mask<<<dim3(64), 256, 0, stream>>>((const unsigned char*)mask, flag);
  gemm1<<<dim3(3072), 256, 0, stream>>>(xb, wq, b_qkv, qkvb, 3 * D, D);
  rownorm_kv<<<dim3(512), 256, 0, stream>>>(qkvb, mask, flag, invq, kv);
  gemm2<<<dim3(1024), 256, 0, stream>>>(qkvb, invq, kv, wo, b_out, out);
}

// Round 5
// 332.431 us; speedup vs baseline: 1.1257x; 1.0025x over previous
//
#include <hip/hip_runtime.h>
#include <stdint.h>

// HydraAttention on MI355X (gfx950), R5.
// Key identity: out = (q_hat . kv_b) @ Wout^T = invq[r] * (q @ (Wout . kv_b)^T) + b.
// So GEMM2 is a pure async-staged GEMM over raw q with per-batch W' = Wout*kv_b,
// invq applied in the epilogue. W' built by scale_w (runs after rownorm).

typedef short  short8   __attribute__((ext_vector_type(8)));
typedef float  floatx16 __attribute__((ext_vector_type(16)));

#define BM 128
#define BN 128
#define BK 64

__device__ __forceinline__ void async16(const void* g, void* l) {
  __builtin_amdgcn_global_load_lds((const __attribute__((address_space(1))) void*)g,
                                   (__attribute__((address_space(3))) void*)l, 16, 0, 0);
}

__device__ __forceinline__ uint16_t f2bf(float f) {  // RNE fp32->bf16
  union { float f; uint32_t u; } x; x.f = f;
  uint32_t u = x.u;
  return (uint16_t)((u + 0x7fffu + ((u >> 16) & 1u)) >> 16);
}
__device__ __forceinline__ float bf2f(uint16_t h) {
  union { uint32_t u; float f; } x; x.u = ((uint32_t)h) << 16; return x.f;
}
__device__ __forceinline__ uint32_t pack2(float a, float b) {
  return (uint32_t)f2bf(a) | ((uint32_t)f2bf(b) << 16);
}
__device__ __forceinline__ void upk8(uint4 u, float* f) {
  f[0]=bf2f((uint16_t)u.x); f[1]=bf2f((uint16_t)(u.x>>16));
  f[2]=bf2f((uint16_t)u.y); f[3]=bf2f((uint16_t)(u.y>>16));
  f[4]=bf2f((uint16_t)u.z); f[5]=bf2f((uint16_t)(u.z>>16));
  f[6]=bf2f((uint16_t)u.w); f[7]=bf2f((uint16_t)(u.w>>16));
}

// ---------------- fused fp32->bf16 convert of 3 buffers ----------------
__global__ __launch_bounds__(256) void cvt3(
    const float* __restrict__ a, uint16_t* __restrict__ ao, int na,
    const float* __restrict__ b, uint16_t* __restrict__ bo, int nb,
    const float* __restrict__ c, uint16_t* __restrict__ co, int nc) {
  int i = blockIdx.x * 256 + threadIdx.x;
  const float* in; uint16_t* out; int j = i;
  if (j < na) { in = a; out = ao; }
  else {
    j -= na;
    if (j < nb) { in = b; out = bo; }
    else { j -= nb; if (j >= nc) return; in = c; out = co; }
  }
  const float4* p = (const float4*)in;
  float4 u = p[(size_t)j * 2], v = p[(size_t)j * 2 + 1];
  uint4 o;
  o.x = pack2(u.x, u.y); o.y = pack2(u.z, u.w);
  o.z = pack2(v.x, v.y); o.w = pack2(v.z, v.w);
  ((uint4*)out)[j] = o;
}

// ---------------- GEMM1: qkv[M,N] = bf16( A[M,K] @ B[N,K]^T + bias ) -------
__global__ __launch_bounds__(256, 2) void gemm1(
    const uint16_t* __restrict__ A, const uint16_t* __restrict__ Bw,
    const float* __restrict__ bias, uint16_t* __restrict__ Cb,
    int N, int K)
{
  __shared__ __align__(16) uint16_t As[BM * BK];
  __shared__ __align__(16) uint16_t Bs[BN * BK];
  const int tid = threadIdx.x;
  const int wave = tid >> 6, lane = tid & 63;
  const int l31 = lane & 31, khalf = lane >> 5;
  const int wm = wave & 1, wn = wave >> 1;
  const int id = blockIdx.x;
  const int xcd = id & 7, w = id >> 3;
  const int tileM = (w / 3) * BM;
  const int tileN = (xcd * 3 + (w % 3)) * BN;

  const int srow = wave * 8 + (lane >> 3);
  const int skc  = (lane & 7) ^ (lane >> 3);
  const uint16_t* gA = A  + (size_t)(tileM + srow) * K + skc * 8;
  const uint16_t* gB = Bw + (size_t)(tileN + srow) * K + skc * 8;
  char* lA = (char*)As + wave * 64 * 16;
  char* lB = (char*)Bs + wave * 64 * 16;

  floatx16 acc[2][2];
#pragma unroll
  for (int mi = 0; mi < 2; mi++)
#pragma unroll
    for (int ni = 0; ni < 2; ni++)
#pragma unroll
      for (int r = 0; r < 16; r++) acc[mi][ni][r] = 0.f;

  const int arow0 = wm * 64 + l31;
  const int brow0 = wn * 64 + l31;

  for (int k0 = 0; k0 < K; k0 += BK) {
#pragma unroll
    for (int s = 0; s < 4; s++) {
      async16(gA + k0 + s * 32 * K, lA + s * 4096);
      async16(gB + k0 + s * 32 * K, lB + s * 4096);
    }
    __syncthreads();
#pragma unroll
    for (int ks = 0; ks < 4; ks++) {
      const int kc = khalf + ks * 2;
      short8 af[2], bfr[2];
#pragma unroll
      for (int mi = 0; mi < 2; mi++) {
        int r = arow0 + mi * 32;
        af[mi] = *(const short8*)&As[(r * 8 + (kc ^ (r & 7))) * 8];
      }
#pragma unroll
      for (int ni = 0; ni < 2; ni++) {
        int r = brow0 + ni * 32;
        bfr[ni] = *(const short8*)&Bs[(r * 8 + (kc ^ (r & 7))) * 8];
      }
#pragma unroll
      for (int mi = 0; mi < 2; mi++)
#pragma unroll
        for (int ni = 0; ni < 2; ni++)
          acc[mi][ni] = __builtin_amdgcn_mfma_f32_32x32x16_bf16(af[mi], bfr[ni], acc[mi][ni], 0, 0, 0);
    }
    __syncthreads();
  }

  // C/D layout 32x32: col = lane&31, row = (reg&3) + 8*(reg>>2) + 4*(lane>>5)
#pragma unroll
  for (int mi = 0; mi < 2; mi++) {
    int rbase = tileM + wm * 64 + mi * 32 + 4 * khalf;
#pragma unroll
    for (int ni = 0; ni < 2; ni++) {
      int col = tileN + wn * 64 + ni * 32 + l31;
      float bv = bias[col];
#pragma unroll
      for (int reg = 0; reg < 16; reg++) {
        int row = rbase + (reg & 3) + 8 * (reg >> 2);
        Cb[(size_t)row * N + col] = f2bf(acc[mi][ni][reg] + bv);
      }
    }
  }
}

// ---------------- GEMM2: out[M,1024] = invq[r]*(q[M,1024] @ W'[1024,1024]^T) + b
// Pure async-staged GEMM. A = q slice of qkv (row stride 3072). B = W'_batch.
__global__ __launch_bounds__(256, 2) void gemm2(
    const uint16_t* __restrict__ qkv, const float* __restrict__ invq,
    const uint16_t* __restrict__ Wp, const float* __restrict__ bias,
    float* __restrict__ Cf)
{
  __shared__ __align__(16) uint16_t As[BM * BK];
  __shared__ __align__(16) uint16_t Bs[BN * BK];
  const int tid = threadIdx.x;
  const int wave = tid >> 6, lane = tid & 63;
  const int l31 = lane & 31, khalf = lane >> 5;
  const int wm = wave & 1, wn = wave >> 1;
  const int id = blockIdx.x;
  const int tileM = (id >> 3) * BM;
  const int tileN = (id & 7) * BN;
  const int batch = tileM >> 12;

  const int srow = wave * 8 + (lane >> 3);
  const int skc  = (lane & 7) ^ (lane >> 3);
  const uint16_t* gA = qkv + (size_t)(tileM + srow) * 3072 + skc * 8;  // q slice
  const uint16_t* gB = Wp + (size_t)batch * 1024 * 1024
                          + (size_t)(tileN + srow) * 1024 + skc * 8;
  char* lA = (char*)As + wave * 64 * 16;
  char* lB = (char*)Bs + wave * 64 * 16;

  floatx16 acc[2][2];
#pragma unroll
  for (int mi = 0; mi < 2; mi++)
#pragma unroll
    for (int ni = 0; ni < 2; ni++)
#pragma unroll
      for (int r = 0; r < 16; r++) acc[mi][ni][r] = 0.f;

  const int arow0 = wm * 64 + l31;
  const int brow0 = wn * 64 + l31;

  for (int k0 = 0; k0 < 1024; k0 += BK) {
#pragma unroll
    for (int s = 0; s < 4; s++) {
      async16(gA + k0 + (size_t)s * 32 * 3072, lA + s * 4096);
      async16(gB + k0 + (size_t)s * 32 * 1024, lB + s * 4096);
    }
    __syncthreads();
#pragma unroll
    for (int ks = 0; ks < 4; ks++) {
      const int kc = khalf + ks * 2;
      short8 af[2], bfr[2];
#pragma unroll
      for (int mi = 0; mi < 2; mi++) {
        int r = arow0 + mi * 32;
        af[mi] = *(const short8*)&As[(r * 8 + (kc ^ (r & 7))) * 8];
      }
#pragma unroll
      for (int ni = 0; ni < 2; ni++) {
        int r = brow0 + ni * 32;
        bfr[ni] = *(const short8*)&Bs[(r * 8 + (kc ^ (r & 7))) * 8];
      }
#pragma unroll
      for (int mi = 0; mi < 2; mi++)
#pragma unroll
        for (int ni = 0; ni < 2; ni++)
          acc[mi][ni] = __builtin_amdgcn_mfma_f32_32x32x16_bf16(af[mi], bfr[ni], acc[mi][ni], 0, 0, 0);
    }
    __syncthreads();
  }

#pragma unroll
  for (int mi = 0; mi < 2; mi++) {
    int rbase = tileM + wm * 64 + mi * 32 + 4 * khalf;
#pragma unroll
    for (int ni = 0; ni < 2; ni++) {
      int col = tileN + wn * 64 + ni * 32 + l31;
      float bv = bias[col];
#pragma unroll
      for (int reg = 0; reg < 16; reg++) {
        int row = rbase + (reg & 3) + 8 * (reg >> 2);
        Cf[(size_t)row * 1024 + col] = fmaf(invq[row], acc[mi][ni][reg], bv);
      }
    }
  }
}

// ---------------- W'[b][n][k] = bf16( Wout[n][k] * kv[b][k] ) ----------------
__global__ __launch_bounds__(256) void scale_w(
    const uint16_t* __restrict__ wo, const float* __restrict__ kv,
    uint16_t* __restrict__ wp)
{
  int i = blockIdx.x * 256 + threadIdx.x;   // 4M elems / 8 = 512K threads
  int e = i << 3;
  int b = e >> 20;
  int k = e & 1023;
  uint4 w = *(const uint4*)(wo + (e & 0xFFFFF));
  float4 k0v = *(const float4*)(kv + (b << 10) + k);
  float4 k1v = *(const float4*)(kv + (b << 10) + k + 4);
  float wf[8]; upk8(w, wf);
  uint4 o;
  o.x = pack2(wf[0] * k0v.x, wf[1] * k0v.y);
  o.y = pack2(wf[2] * k0v.z, wf[3] * k0v.w);
  o.z = pack2(wf[4] * k1v.x, wf[5] * k1v.y);
  o.w = pack2(wf[6] * k1v.z, wf[7] * k1v.w);
  *(uint4*)(wp + e) = o;
}

// ---------------- mask layout detection ----------------
__global__ __launch_bounds__(256) void detect_mask(const unsigned char* __restrict__ m,
                                                   int* __restrict__ flag) {
  int i = blockIdx.x * blockDim.x + threadIdx.x;
  int v = ((i & 3) != 0) ? (int)m[i] : 0;
  unsigned long long b = __ballot(v != 0);
  if ((threadIdx.x & 63) == 0 && b) atomicOr(flag, 1);
}

// ---------------- per-row norms + kv reduction (512 blocks) ----------------
__global__ __launch_bounds__(256) void rownorm_kv(
    const uint16_t* __restrict__ qkv, const void* __restrict__ maskbuf,
    const int* __restrict__ flag, float* __restrict__ invq, float* __restrict__ kv)
{
  __shared__ float kvloc[1024];
  const int tid = threadIdx.x;
  for (int i = tid; i < 1024; i += 256) kvloc[i] = 0.f;
  __syncthreads();
  const int wave = tid >> 6, lane = tid & 63;
  const int b = blockIdx.x >> 7;
  const int chunk = blockIdx.x & 127;
  const int isU8 = *flag;
  const unsigned char* m8 = (const unsigned char*)maskbuf;
  const int* m32 = (const int*)maskbuf;

  float kvacc[16];
#pragma unroll
  for (int i = 0; i < 16; i++) kvacc[i] = 0.f;

  const int r0 = b * 4096 + chunk * 32 + wave * 8;
#pragma unroll 2
  for (int j = 0; j < 8; j++) {
    int r = r0 + j;
    const uint16_t* rp = qkv + (size_t)r * 3072;
    uint4 q0 = *(const uint4*)(rp + lane * 16);
    uint4 q1 = *(const uint4*)(rp + lane * 16 + 8);
    uint4 k0 = *(const uint4*)(rp + 1024 + lane * 16);
    uint4 k1 = *(const uint4*)(rp + 1024 + lane * 16 + 8);
    uint4 v0 = *(const uint4*)(rp + 2048 + lane * 16);
    uint4 v1 = *(const uint4*)(rp + 2048 + lane * 16 + 8);
    float qf[16], kf[16], vf[16];
    upk8(q0, qf); upk8(q1, qf + 8);
    upk8(k0, kf); upk8(k1, kf + 8);
    upk8(v0, vf); upk8(v1, vf + 8);
    float sq = 0.f, sk = 0.f;
#pragma unroll
    for (int i = 0; i < 16; i++) { sq = fmaf(qf[i], qf[i], sq); sk = fmaf(kf[i], kf[i], sk); }
    for (int off = 32; off; off >>= 1) { sq += __shfl_xor(sq, off); sk += __shfl_xor(sk, off); }
    float rq = rsqrtf(sq), rk = rsqrtf(sk);
    if (lane == 0) invq[r] = rq;
    int masked = isU8 ? (int)m8[r] : m32[r];
    if (!masked) {
#pragma unroll
      for (int i = 0; i < 16; i++) kvacc[i] = fmaf(kf[i] * rk, vf[i], kvacc[i]);
    }
  }
#pragma unroll
  for (int i = 0; i < 16; i++) atomicAdd(&kvloc[lane * 16 + i], kvacc[i]);
  __syncthreads();
  for (int i = tid; i < 1024; i += 256) atomicAdd(&kv[b * 1024 + i], kvloc[i]);
}

extern "C" void kernel_launch(void* const* d_in, const int* in_sizes, int n_in,
                              void* d_out, int out_size, void* d_ws, size_t ws_size,
                              hipStream_t stream) {
  const float* x     = (const float*)d_in[0];
  const void*  mask  = d_in[1];
  const float* W_qkv = (const float*)d_in[2];
  const float* b_qkv = (const float*)d_in[3];
  const float* W_out = (const float*)d_in[4];
  const float* b_out = (const float*)d_in[5];
  float* out = (float*)d_out;

  const int BT = 4 * 4096;  // 16384 rows
  const int D  = 1024;

  char* ws = (char*)d_ws;
  size_t off = 0;
  auto alloc = [&](size_t bytes) { size_t r = off; off += (bytes + 255) & ~(size_t)255; return r; };
  size_t o_xb   = alloc((size_t)BT * D * 2);        // x bf16
  size_t o_qkvb = alloc((size_t)BT * 3 * D * 2);    // qkv bf16
  size_t o_wq   = alloc((size_t)3 * D * D * 2);     // W_qkv bf16
  size_t o_wo   = alloc((size_t)D * D * 2);         // W_out bf16
  size_t o_wp   = alloc((size_t)4 * D * D * 2);     // W' = Wout*kv_b, per batch
  size_t o_kv   = alloc((size_t)4 * D * 4 + 256);   // kv (fp32) + flag
  size_t o_invq = alloc((size_t)BT * 4);            // 1/||q|| per row

  uint16_t* xb   = (uint16_t*)(ws + o_xb);
  uint16_t* qkvb = (uint16_t*)(ws + o_qkvb);
  uint16_t* wq   = (uint16_t*)(ws + o_wq);
  uint16_t* wo   = (uint16_t*)(ws + o_wo);
  uint16_t* wp   = (uint16_t*)(ws + o_wp);
  float*    kv   = (float*)(ws + o_kv);
  int*      flag = (int*)(ws + o_kv + (size_t)4 * D * 4);
  float*    invq = (float*)(ws + o_invq);

  hipMemsetAsync(ws + o_kv, 0, (size_t)4 * D * 4 + 256, stream);
  {
    int na = BT * D / 8, nb = 3 * D * D / 8, nc = D * D / 8;
    int tot = na + nb + nc;
    cvt3<<<dim3((tot + 255) / 256), 256, 0, stream>>>(x, xb, na, W_qkv, wq, nb, W_out, wo, nc);
  }
  detect_mask<<<dim3(64), 256, 0, stream>>>((const unsigned char*)mask, flag);
  gemm1<<<dim3(3072), 256, 0, stream>>>(xb, wq, b_qkv, qkvb, 3 * D, D);
  rownorm_kv<<<dim3(512), 256, 0, stream>>>(qkvb, mask, flag, invq, kv);
  scale_w<<<dim3(4 * D * D / 8 / 256), 256, 0, stream>>>(wo, kv, wp);
  gemm2<<<dim3(1024), 256, 0, stream>>>(qkvb, invq, wp, b_out, out);
}